// Round 2
// 3931.404 us; speedup vs baseline: 1.3593x; 1.3593x over previous
//
#include <hip/hip_runtime.h>
#include <cstdio>
#include <cmath>

#define HIDDEN 768
#define HEADS 8
#define DHEAD 96
#define NLAYERS 2
#define HH (HIDDEN * HIDDEN)

typedef unsigned short u16;
typedef unsigned int u32;
typedef __attribute__((ext_vector_type(8))) short bf16x8;
typedef __attribute__((ext_vector_type(4))) float f32x4;

__device__ __forceinline__ u16 f2b(float f) {
    u32 u = __float_as_uint(f);
    u32 r = (u + 0x7FFFu + ((u >> 16) & 1u)) >> 16;
    return (u16)r;
}
__device__ __forceinline__ float b2f(u16 v) { return __uint_as_float(((u32)v) << 16); }

// ================================================================== MFMA GEMM
// C[M,N] = act(A[M,K] @ Wt[N,K]^T + bias). A, Wt bf16 (u16) row-major,
// K contiguous for both. M multiple of 128, N multiple of 128, K multiple of 32.
// 128x128 tile, BK=32, 256 threads (4 waves, 2x2 of 64x64), 16x16x32 MFMA.
// LDS chunk swizzle s(r)=(r>>1)&3 keeps frag reads at 2-way (free).
template<int OUTF, int OUTB, int ACT>
__global__ __launch_bounds__(256, 3)
void gemm_mfma(const u16* __restrict__ A, const u16* __restrict__ Wt,
               const float* __restrict__ bias,
               float* __restrict__ Cf, u16* __restrict__ Cb,
               int M, int N, int K)
{
    __shared__ u16 As[128 * 32];
    __shared__ u16 Bs[128 * 32];
    const int tid = threadIdx.x;
    const int lane = tid & 63;
    const int wave = tid >> 6;
    const long m0 = (long)blockIdx.x * 128;
    const long n0 = (long)blockIdx.y * 128;
    const int wm = (wave & 1) * 64;
    const int wn = (wave >> 1) * 64;

    f32x4 acc[4][4];
#pragma unroll
    for (int i = 0; i < 4; i++)
#pragma unroll
        for (int j = 0; j < 4; j++) acc[i][j] = (f32x4){0.f, 0.f, 0.f, 0.f};

    // staging map: ci in {tid, tid+256}; row r=ci>>2, lds pos p=ci&3,
    // global chunk g = p ^ ((r>>1)&3)
    const int r0 = tid >> 2, p0 = tid & 3;
    const int g0 = p0 ^ ((r0 >> 1) & 3);
    const int r1 = r0 + 64;
    const int g1 = p0 ^ ((r1 >> 1) & 3);
    const u16* ga0 = A + (m0 + r0) * (long)K + g0 * 8;
    const u16* ga1 = A + (m0 + r1) * (long)K + g1 * 8;
    const u16* gb0 = Wt + (n0 + r0) * (long)K + g0 * 8;
    const u16* gb1 = Wt + (n0 + r1) * (long)K + g1 * 8;
    u16* la0 = As + tid * 8;
    u16* la1 = As + (tid + 256) * 8;
    u16* lb0 = Bs + tid * 8;
    u16* lb1 = Bs + (tid + 256) * 8;

    for (int k0 = 0; k0 < K; k0 += 32) {
        __builtin_amdgcn_global_load_lds((const __attribute__((address_space(1))) void*)(ga0 + k0),
                                         (__attribute__((address_space(3))) void*)la0, 16, 0, 0);
        __builtin_amdgcn_global_load_lds((const __attribute__((address_space(1))) void*)(ga1 + k0),
                                         (__attribute__((address_space(3))) void*)la1, 16, 0, 0);
        __builtin_amdgcn_global_load_lds((const __attribute__((address_space(1))) void*)(gb0 + k0),
                                         (__attribute__((address_space(3))) void*)lb0, 16, 0, 0);
        __builtin_amdgcn_global_load_lds((const __attribute__((address_space(1))) void*)(gb1 + k0),
                                         (__attribute__((address_space(3))) void*)lb1, 16, 0, 0);
        __syncthreads();

        bf16x8 af[4], bfr[4];
        const int q = lane >> 4;
        const int lr = lane & 15;
#pragma unroll
        for (int i = 0; i < 4; i++) {
            int rr = wm + i * 16 + lr;
            af[i] = *(const bf16x8*)(As + rr * 32 + ((q ^ ((rr >> 1) & 3)) * 8));
            int rn = wn + i * 16 + lr;
            bfr[i] = *(const bf16x8*)(Bs + rn * 32 + ((q ^ ((rn >> 1) & 3)) * 8));
        }
#pragma unroll
        for (int i = 0; i < 4; i++)
#pragma unroll
            for (int j = 0; j < 4; j++)
                acc[i][j] = __builtin_amdgcn_mfma_f32_16x16x32_bf16(af[i], bfr[j], acc[i][j], 0, 0, 0);
        __syncthreads();
    }

    const int lc = lane & 15, lq = lane >> 4;
#pragma unroll
    for (int j = 0; j < 4; j++) {
        long col = n0 + wn + j * 16 + lc;
        float bv = bias ? bias[col] : 0.f;
#pragma unroll
        for (int i = 0; i < 4; i++) {
#pragma unroll
            for (int rg = 0; rg < 4; rg++) {
                long row = m0 + wm + i * 16 + lq * 4 + rg;
                float v = acc[i][j][rg] + bv;
                if (ACT) v = fmaxf(v, 0.f);
                if (OUTF) Cf[row * N + col] = v;
                if (OUTB) Cb[row * N + col] = f2b(v);
            }
        }
    }
}

// ================================================================== f32 GEMM
// (kept for the tiny combined-weight GEMMs: M=768, N=96, K=96, batch=heads)
template<int ACT>
__global__ void gemm_f32(const float* __restrict__ A, int lda, long sA,
                         const float* __restrict__ W, int ldw, long sW,
                         const float* __restrict__ bias, long sB,
                         float* __restrict__ C, int ldc, long sC,
                         int M, int N, int K)
{
    int bz = blockIdx.z;
    A += (long)bz * sA;
    W += (long)bz * sW;
    C += (long)bz * sC;
    if (bias) bias += (long)bz * sB;

    __shared__ float Ash[16][65];
    __shared__ float Wsh[16][65];

    int tid = threadIdx.x;
    int tx = tid & 15, ty = tid >> 4;
    int m0 = blockIdx.x * 64, n0 = blockIdx.y * 64;
    float acc[4][4] = {};

    for (int k0 = 0; k0 < K; k0 += 16) {
#pragma unroll
        for (int i = 0; i < 4; i++) {
            int t = tid + i * 256;
            int mm = t >> 4, kk = t & 15;
            int gm = m0 + mm;
            Ash[kk][mm] = (gm < M) ? A[(long)gm * lda + (k0 + kk)] : 0.f;
        }
#pragma unroll
        for (int i = 0; i < 4; i++) {
            int t = tid + i * 256;
            int kk = t >> 6, nn = t & 63;
            int gn = n0 + nn;
            Wsh[kk][nn] = (gn < N) ? W[(long)(k0 + kk) * ldw + gn] : 0.f;
        }
        __syncthreads();
#pragma unroll
        for (int kk = 0; kk < 16; kk++) {
            float a[4], w[4];
#pragma unroll
            for (int i = 0; i < 4; i++) a[i] = Ash[kk][ty * 4 + i];
#pragma unroll
            for (int j = 0; j < 4; j++) w[j] = Wsh[kk][tx * 4 + j];
#pragma unroll
            for (int i = 0; i < 4; i++)
#pragma unroll
                for (int j = 0; j < 4; j++) acc[i][j] = fmaf(a[i], w[j], acc[i][j]);
        }
        __syncthreads();
    }
#pragma unroll
    for (int i = 0; i < 4; i++) {
        int gm = m0 + ty * 4 + i;
        if (gm >= M) continue;
#pragma unroll
        for (int j = 0; j < 4; j++) {
            int gn = n0 + tx * 4 + j;
            if (gn >= N) continue;
            float v = acc[i][j];
            if (bias) v += bias[gn];
            if (ACT == 1) v = fmaxf(v, 0.f);
            C[(long)gm * ldc + gn] = v;
        }
    }
}

// ================================================================== prep
// f32 [768][768] -> bf16 [768][768] transposed, batched
__global__ void transpose_f2b(const float* __restrict__ src, long sStride,
                              u16* __restrict__ dst, long dStride)
{
    __shared__ float t[32][33];
    int z = blockIdx.z;
    src += (long)z * sStride;
    dst += (long)z * dStride;
    int bx = blockIdx.x * 32, by = blockIdx.y * 32;
    int x = threadIdx.x, y = threadIdx.y;  // 32 x 8
#pragma unroll
    for (int i = 0; i < 32; i += 8)
        t[y + i][x] = src[(long)(by + y + i) * 768 + bx + x];
    __syncthreads();
#pragma unroll
    for (int i = 0; i < 32; i += 8)
        dst[(long)(bx + y + i) * 768 + by + x] = f2b(t[x][y + i]);
}

// combined bias: bc[combo][h*96+j] = sum_d kb_slice[h*96+d] * R[l,e,h,d,j]
__global__ void bias_comb_k(const float* __restrict__ kb, const float* __restrict__ aR,
                            const float* __restrict__ mR, float* __restrict__ bc)
{
    int idx = blockIdx.x * blockDim.x + threadIdx.x;
    if (idx >= 12 * 768) return;
    int combo = idx / 768;
    int x = idx % 768;
    int h = x / 96, j = x % 96;
    int c6 = combo % 6;
    int l = c6 / 3, e = c6 % 3;
    int kind = (combo < 6) ? 0 : 2;
    int st = (e == 1) ? 1 : 0;
    const float* R = ((combo < 6) ? aR : mR) + ((long)(l * 3 + e) * 8 + h) * 9216;
    const float* kbp = kb + ((long)(l * 2 + st) * 4 + kind) * 768 + h * 96;
    float s = 0.f;
#pragma unroll 8
    for (int d = 0; d < 96; d++) s = fmaf(kbp[d], R[d * 96 + j], s);
    bc[idx] = s;
}

// x f32 -> bf16, zero-fill pad rows
__global__ void conv_pad(const float* __restrict__ src, u16* __restrict__ dst,
                         long nReal, long nPad)
{
    long i = blockIdx.x * (long)blockDim.x + threadIdx.x;
    if (i >= nPad) return;
    dst[i] = (i < nReal) ? f2b(src[i]) : (u16)0;
}

// ================================================================== pointwise
__global__ void fill_f32(float* __restrict__ p, float v, long n) {
    long i = blockIdx.x * (long)blockDim.x + threadIdx.x;
    if (i < n) p[i] = v;
}

// out_bf = relu(beta*o + (1-beta)*h); optionally also write f32
__global__ void skip_k(const float* __restrict__ o, const u16* __restrict__ hin,
                       const float* __restrict__ sp, u16* __restrict__ outb,
                       float* __restrict__ outf, long n)
{
    long i = blockIdx.x * (long)blockDim.x + threadIdx.x;
    if (i < n) {
        float beta = 1.f / (1.f + expf(-sp[0]));
        float v = beta * o[i] + (1.f - beta) * b2f(hin[i]);
        v = fmaxf(v, 0.f);
        outb[i] = f2b(v);
        if (outf) outf[i] = v;
    }
}

// ================================================================== edge ops
__device__ __forceinline__ float bdot(u32 a, u32 b, float s) {
    float al = __uint_as_float(a << 16);
    float ah = __uint_as_float(a & 0xffff0000u);
    float bl = __uint_as_float(b << 16);
    float bh = __uint_as_float(b & 0xffff0000u);
    return fmaf(ah, bh, fmaf(al, bl, s));
}

__global__ void edge_logits(const u16* __restrict__ q, const u16* __restrict__ kt,
                            const int* __restrict__ src, const int* __restrict__ dst,
                            const float* __restrict__ prel, float* __restrict__ out,
                            int ne)
{
    int idx = blockIdx.x * blockDim.x + threadIdx.x;
    if (idx >= ne * HEADS) return;
    int e = idx >> 3, h = idx & 7;
    const u16* qr = q + (long)dst[e] * HIDDEN + h * DHEAD;
    const u16* kr = kt + (long)src[e] * HIDDEN + h * DHEAD;
    float s = 0.f;
#pragma unroll
    for (int c = 0; c < 12; c++) {
        uint4 qv = *(const uint4*)(qr + c * 8);
        uint4 kv = *(const uint4*)(kr + c * 8);
        s = bdot(qv.x, kv.x, s);
        s = bdot(qv.y, kv.y, s);
        s = bdot(qv.z, kv.z, s);
        s = bdot(qv.w, kv.w, s);
    }
    out[idx] = s * prel[h] * 0.1020620726159658f;  // 1/sqrt(96)
}

__device__ __forceinline__ void atomicMaxF(float* addr, float val) {
    int* ia = (int*)addr;
    int cur = __float_as_int(*addr);
    while (__int_as_float(cur) < val) {
        int assumed = cur;
        cur = atomicCAS(ia, assumed, __float_as_int(val));
        if (cur == assumed) break;
    }
}

__global__ void seg_max_k(const float* __restrict__ lg, const int* __restrict__ dst,
                          float* __restrict__ dmax, int ne) {
    int idx = blockIdx.x * blockDim.x + threadIdx.x;
    if (idx >= ne * HEADS) return;
    int e = idx >> 3, h = idx & 7;
    atomicMaxF(&dmax[(long)dst[e] * HEADS + h], lg[idx]);
}

// lg <- exp(lg - max); denom accumulates exp values (NOT normalized; the
// per-(dst,h) division is folded into the gather kernel)
__global__ void seg_expsum_k(float* __restrict__ lg, const int* __restrict__ dst,
                             const float* __restrict__ dmax, float* __restrict__ denom,
                             int ne) {
    int idx = blockIdx.x * blockDim.x + threadIdx.x;
    if (idx >= ne * HEADS) return;
    int e = idx >> 3, h = idx & 7;
    float v = expf(lg[idx] - dmax[(long)dst[e] * HEADS + h]);
    lg[idx] = v;
    atomicAdd(&denom[(long)dst[e] * HEADS + h], v);
}

// ================================================================== CSR build
// (edge indices are static across layers -> built once per call)
__global__ void hist_k(const int* __restrict__ dst, int* __restrict__ cnt, int ne) {
    int i = blockIdx.x * blockDim.x + threadIdx.x;
    if (i < ne) atomicAdd(&cnt[dst[i]], 1);
}

// single-block exclusive scan, 1024 thr x 8 elems/chunk; out has n+1 entries
__global__ void excl_scan_k(const int* __restrict__ in, int* __restrict__ out, int n)
{
    __shared__ int lds[1024];
    __shared__ int carry_s;
    const int tid = threadIdx.x;
    if (tid == 0) carry_s = 0;
    __syncthreads();
    for (int base = 0; base < n; base += 8192) {
        int v[8];
        int s = 0;
        const int i0 = base + tid * 8;
#pragma unroll
        for (int j = 0; j < 8; j++) {
            v[j] = s;
            int idx = i0 + j;
            s += (idx < n) ? in[idx] : 0;
        }
        lds[tid] = s;
        __syncthreads();
        int cb = carry_s;
        for (int ofs = 1; ofs < 1024; ofs <<= 1) {
            int t = (tid >= ofs) ? lds[tid - ofs] : 0;
            __syncthreads();
            if (tid >= ofs) lds[tid] += t;
            __syncthreads();
        }
        int excl = cb + (tid ? lds[tid - 1] : 0);
#pragma unroll
        for (int j = 0; j < 8; j++) {
            int idx = i0 + j;
            if (idx < n) out[idx] = excl + v[j];
        }
        __syncthreads();
        if (tid == 0) carry_s = cb + lds[1023];
        __syncthreads();
    }
    if (tid == 0) out[n] = carry_s;
}

__global__ void scatter_perm_k(const int* __restrict__ dst, const int* __restrict__ rs,
                               int* __restrict__ cur, int* __restrict__ ep, int ne) {
    int i = blockIdx.x * blockDim.x + threadIdx.x;
    if (i < ne) {
        int d = dst[i];
        int p = rs[d] + atomicAdd(&cur[d], 1);
        ep[p] = i;
    }
}

// ================================================================== gather
// One block per dst node; 192 threads x 4 channels. Accumulates
// sum_e alpha_e * vt[src_e] over up to two CSR edge sets, divides by the
// per-(node,h) softmax denom, applies GELU, writes bf16 row (pad rows -> 0).
__device__ __forceinline__ void fma4bf(uint2 pv, float a, float acc[4]) {
    acc[0] = fmaf(a, __uint_as_float(pv.x << 16), acc[0]);
    acc[1] = fmaf(a, __uint_as_float(pv.x & 0xffff0000u), acc[1]);
    acc[2] = fmaf(a, __uint_as_float(pv.y << 16), acc[2]);
    acc[3] = fmaf(a, __uint_as_float(pv.y & 0xffff0000u), acc[3]);
}

template<int NSET>
__global__ void gather_gelu_k(
    const int* __restrict__ rs0, const int* __restrict__ ep0, const int* __restrict__ src0,
    const float* __restrict__ al0, const float* __restrict__ den0, const u16* __restrict__ vt0,
    const int* __restrict__ rs1, const int* __restrict__ ep1, const int* __restrict__ src1,
    const float* __restrict__ al1, const float* __restrict__ den1, const u16* __restrict__ vt1,
    u16* __restrict__ out, int nsReal)
{
    const int node = blockIdx.x;
    const int tid = threadIdx.x;           // 192
    const int h = tid / 24;                // 24 threads per head (96 ch / 4)
    float acc[4] = {0.f, 0.f, 0.f, 0.f};
    if (node < nsReal) {
        {
            const int b = rs0[node], en = rs0[node + 1];
            float part[4] = {0.f, 0.f, 0.f, 0.f};
            for (int i = b; i < en; i++) {
                const int eid = ep0[i];
                const float a = al0[(long)eid * HEADS + h];
                const uint2 pv = *(const uint2*)(vt0 + (long)src0[eid] * HIDDEN + tid * 4);
                fma4bf(pv, a, part);
            }
            const float r = 1.f / (den0[(long)node * HEADS + h] + 1e-16f);
#pragma unroll
            for (int j = 0; j < 4; j++) acc[j] = part[j] * r;
        }
        if (NSET == 2) {
            const int b = rs1[node], en = rs1[node + 1];
            float part[4] = {0.f, 0.f, 0.f, 0.f};
            for (int i = b; i < en; i++) {
                const int eid = ep1[i];
                const float a = al1[(long)eid * HEADS + h];
                const uint2 pv = *(const uint2*)(vt1 + (long)src1[eid] * HIDDEN + tid * 4);
                fma4bf(pv, a, part);
            }
            const float r = 1.f / (den1[(long)node * HEADS + h] + 1e-16f);
#pragma unroll
            for (int j = 0; j < 4; j++) acc[j] = fmaf(part[j], r, acc[j]);
        }
    }
    // exact GELU, pack to bf16, single 8B store
    float g[4];
#pragma unroll
    for (int j = 0; j < 4; j++)
        g[j] = 0.5f * acc[j] * (1.f + erff(acc[j] * 0.70710678118654752f));
    u32 w0 = (u32)f2b(g[0]) | ((u32)f2b(g[1]) << 16);
    u32 w1 = (u32)f2b(g[2]) | ((u32)f2b(g[3]) << 16);
    *(uint2*)(out + (long)node * HIDDEN + tid * 4) = make_uint2(w0, w1);
}

// ================================================================== host
static inline void mfma_bf16out(hipStream_t s, const u16* A, const u16* Wt,
                                const float* bias, u16* Cb, int M, int act) {
    dim3 grid(M / 128, HIDDEN / 128);
    if (act)
        gemm_mfma<0, 1, 1><<<grid, 256, 0, s>>>(A, Wt, bias, nullptr, Cb, M, HIDDEN, HIDDEN);
    else
        gemm_mfma<0, 1, 0><<<grid, 256, 0, s>>>(A, Wt, bias, nullptr, Cb, M, HIDDEN, HIDDEN);
}
static inline void mfma_f32out(hipStream_t s, const u16* A, const u16* Wt,
                               const float* bias, float* Cf, int M) {
    dim3 grid(M / 128, HIDDEN / 128);
    gemm_mfma<1, 0, 0><<<grid, 256, 0, s>>>(A, Wt, bias, Cf, nullptr, M, HIDDEN, HIDDEN);
}

extern "C" void kernel_launch(void* const* d_in, const int* in_sizes, int n_in,
                              void* d_out, int out_size, void* d_ws, size_t ws_size,
                              hipStream_t stream)
{
    const float* x0  = (const float*)d_in[0];
    const float* x1  = (const float*)d_in[1];
    const float* nlW = (const float*)d_in[2];
    const float* nlb = (const float*)d_in[3];
    const float* kW  = (const float*)d_in[4];   // [L,2,4,768,768]
    const float* kb  = (const float*)d_in[5];   // [L,2,4,768]
    const float* skp = (const float*)d_in[6];   // [L,2]
    const float* aR  = (const float*)d_in[7];   // [L,3,8,96,96]
    const float* mR  = (const float*)d_in[8];   // [L,3,8,96,96]
    const float* pR  = (const float*)d_in[9];   // [L,3,8]
    const int* esrc[3] = {(const int*)d_in[10], (const int*)d_in[12], (const int*)d_in[14]};
    const int* edst[3] = {(const int*)d_in[11], (const int*)d_in[13], (const int*)d_in[15]};
    const int EST[3] = {0, 1, 0};
    const int EDT[3] = {0, 0, 1};
    const int EN[3]  = {in_sizes[10], in_sizes[12], in_sizes[14]};

    const int NP = in_sizes[0] / HIDDEN;
    const int NA = in_sizes[1] / HIDDEN;
    const int ns[2]    = {NP, NA};
    const int nspad[2] = {(NP + 127) & ~127, (NA + 127) & ~127};

    // ---------------- workspace (bytes, 256-aligned) ----------------
    char* base = (char*)d_ws;
    size_t off = 0;
    auto alloc = [&](size_t bytes) -> void* {
        void* p = base + off;
        off += (bytes + 255) & ~(size_t)255;
        return p;
    };
    u16* hbf[2] = {(u16*)alloc((size_t)nspad[0] * HIDDEN * 2),
                   (u16*)alloc((size_t)nspad[1] * HIDDEN * 2)};
    u16* qbf[2] = {(u16*)alloc((size_t)nspad[0] * HIDDEN * 2),   // also x-bf16, gelu-bf16
                   (u16*)alloc((size_t)nspad[1] * HIDDEN * 2)};
    u16* ktvbase = (u16*)alloc((size_t)(2 * nspad[0] + nspad[1]) * HIDDEN * 2);
    u16* ktv[3] = {ktvbase, ktvbase + (size_t)nspad[0] * HIDDEN,
                   ktvbase + (size_t)(nspad[0] + nspad[1]) * HIDDEN};
    float* Obuf = (float*)ktvbase;                               // phase-C reuse
    float* alphab[3];
    for (int e = 0; e < 3; e++) alphab[e] = (float*)alloc((size_t)EN[e] * HEADS * 4);
    float* dmax = (float*)alloc((size_t)nspad[0] * HEADS * 4);
    float* denomE[3];
    for (int e = 0; e < 3; e++) denomE[e] = (float*)alloc((size_t)nspad[EDT[e]] * HEADS * 4);
    int* csr_rs[3];
    int* csr_ep[3];
    for (int e = 0; e < 3; e++) {
        csr_rs[e] = (int*)alloc((size_t)(ns[EDT[e]] + 1) * 4);
        csr_ep[e] = (int*)alloc((size_t)EN[e] * 4);
    }
    int nsMax = ns[0] > ns[1] ? ns[0] : ns[1];
    int* cursor = (int*)alloc((size_t)nsMax * 4);
    u16* Wbf     = (u16*)alloc((size_t)22 * HH * 2);   // transposed bf16 weights
    float* Wcomb = (float*)alloc((size_t)12 * HH * 4); // combined f32 weights
    float* bcomb = (float*)alloc((size_t)12 * 768 * 4);
    if (off > ws_size)
        fprintf(stderr, "kernel_launch: ws too small: need %zu have %zu\n", off, ws_size);

    auto wslot = [&](int s) { return Wbf + (size_t)s * HH; };

    // ---------------- CSR build (edges static across layers) ----------------
    for (int e = 0; e < 3; e++) {
        int dt = EDT[e], Ne = EN[e], nd = ns[dt];
        hipMemsetAsync(cursor, 0, (size_t)nd * 4, stream);
        hist_k<<<(Ne + 255) / 256, 256, 0, stream>>>(edst[e], cursor, Ne);
        excl_scan_k<<<1, 1024, 0, stream>>>(cursor, csr_rs[e], nd);
        hipMemsetAsync(cursor, 0, (size_t)nd * 4, stream);
        scatter_perm_k<<<(Ne + 255) / 256, 256, 0, stream>>>(edst[e], csr_rs[e], cursor,
                                                             csr_ep[e], Ne);
    }

    // ---------------- weight prep ----------------
    // combined kt/vt weights: Wc = Wk_slice[768x96] @ R[h][96x96], head-batched
    for (int l = 0; l < NLAYERS; l++)
        for (int e = 0; e < 3; e++) {
            int st = EST[e];
            {   // kt (kind 0, aR)
                const float* Ap = kW + ((size_t)(l * 2 + st) * 4 + 0) * HH;
                const float* Wp = aR + ((size_t)(l * 3 + e)) * 8 * 9216;
                float* Cp = Wcomb + (size_t)(l * 3 + e) * HH;
                dim3 g(12, 2, 8);
                gemm_f32<0><<<g, 256, 0, stream>>>(Ap, 768, 96, Wp, 96, 9216,
                                                   nullptr, 0, Cp, 768, 96, 768, 96, 96);
            }
            {   // vt (kind 2, mR)
                const float* Ap = kW + ((size_t)(l * 2 + st) * 4 + 2) * HH;
                const float* Wp = mR + ((size_t)(l * 3 + e)) * 8 * 9216;
                float* Cp = Wcomb + (size_t)(6 + l * 3 + e) * HH;
                dim3 g(12, 2, 8);
                gemm_f32<0><<<g, 256, 0, stream>>>(Ap, 768, 96, Wp, 96, 9216,
                                                   nullptr, 0, Cp, 768, 96, 768, 96, 96);
            }
        }
    bias_comb_k<<<(12 * 768 + 255) / 256, 256, 0, stream>>>(kb, aR, mR, bcomb);

    // transpose-convert weights to bf16 [N][K]
    {
        dim3 b(32, 8);
        dim3 g(24, 24, 2);
        transpose_f2b<<<g, b, 0, stream>>>(nlW, HH, wslot(0), HH);          // node: slots 0,1
        g.z = 4;
        transpose_f2b<<<g, b, 0, stream>>>(kW + (size_t)1 * HH, 4 * (long)HH, wslot(2), HH); // Q: 2..5
        transpose_f2b<<<g, b, 0, stream>>>(kW + (size_t)3 * HH, 4 * (long)HH, wslot(6), HH); // A: 6..9
        g.z = 6;
        transpose_f2b<<<g, b, 0, stream>>>(Wcomb, HH, wslot(10), HH);                // kcomb: 10..15
        transpose_f2b<<<g, b, 0, stream>>>(Wcomb + (size_t)6 * HH, HH, wslot(16), HH); // vcomb: 16..21
    }

    // ---------------- input projection ----------------
    for (int t = 0; t < 2; t++) {
        long nPad = (long)nspad[t] * HIDDEN, nReal = (long)ns[t] * HIDDEN;
        conv_pad<<<(int)((nPad + 255) / 256), 256, 0, stream>>>(t ? x1 : x0, qbf[t], nReal, nPad);
        mfma_bf16out(stream, qbf[t], wslot(t), nlb + (size_t)t * 768, hbf[t], nspad[t], 1);
    }

    // ---------------- layers ----------------
    for (int l = 0; l < NLAYERS; l++) {
        // phase A: Q + kt projections, logits, segment softmax (denom kept)
        for (int t = 0; t < 2; t++)
            mfma_bf16out(stream, hbf[t], wslot(2 + l * 2 + t),
                         kb + ((size_t)(l * 2 + t) * 4 + 1) * 768, qbf[t], nspad[t], 0);
        for (int e = 0; e < 3; e++) {
            int st = EST[e], dt = EDT[e], Ne = EN[e];
            mfma_bf16out(stream, hbf[st], wslot(10 + l * 3 + e),
                         bcomb + (size_t)(l * 3 + e) * 768, ktv[e], nspad[st], 0);
            int nthr = Ne * HEADS;
            edge_logits<<<(nthr + 255) / 256, 256, 0, stream>>>(
                qbf[dt], ktv[e], esrc[e], edst[e],
                pR + ((size_t)l * 3 + e) * HEADS, alphab[e], Ne);
            long nd = (long)ns[dt] * HEADS;
            fill_f32<<<(int)((nd + 255) / 256), 256, 0, stream>>>(dmax, -INFINITY, nd);
            hipMemsetAsync(denomE[e], 0, nd * sizeof(float), stream);
            seg_max_k<<<(nthr + 255) / 256, 256, 0, stream>>>(alphab[e], edst[e], dmax, Ne);
            seg_expsum_k<<<(nthr + 255) / 256, 256, 0, stream>>>(alphab[e], edst[e], dmax,
                                                                 denomE[e], Ne);
        }
        // phase B: vt projections, then CSR gather (fused denom-div + GELU -> bf16)
        for (int e = 0; e < 3; e++) {
            int st = EST[e];
            mfma_bf16out(stream, hbf[st], wslot(16 + l * 3 + e),
                         bcomb + (size_t)(6 + l * 3 + e) * 768, ktv[e], nspad[st], 0);
        }
        // paper aggr: edge sets 0 (pp) and 1 (ap)
        gather_gelu_k<2><<<nspad[0], 192, 0, stream>>>(
            csr_rs[0], csr_ep[0], esrc[0], alphab[0], denomE[0], ktv[0],
            csr_rs[1], csr_ep[1], esrc[1], alphab[1], denomE[1], ktv[1],
            qbf[0], ns[0]);
        // author aggr: edge set 2 (pa)
        gather_gelu_k<1><<<nspad[1], 192, 0, stream>>>(
            csr_rs[2], csr_ep[2], esrc[2], alphab[2], denomE[2], ktv[2],
            nullptr, nullptr, nullptr, nullptr, nullptr, nullptr,
            qbf[1], ns[1]);
        // phase C: A-projection -> skip/relu (GELU already fused into gather)
        for (int t = 0; t < 2; t++) {
            long nReal = (long)ns[t] * HIDDEN;
            mfma_f32out(stream, qbf[t], wslot(6 + l * 2 + t),
                        kb + ((size_t)(l * 2 + t) * 4 + 3) * 768, Obuf, nspad[t]);
            float* outf = (l == NLAYERS - 1)
                        ? ((float*)d_out + (t == 0 ? 0 : (size_t)NP * HIDDEN))
                        : nullptr;
            skip_k<<<(int)((nReal + 255) / 256), 256, 0, stream>>>(
                Obuf, hbf[t], skp + (size_t)l * 2 + t, hbf[t], outf, nReal);
        }
    }
}

// Round 3
// 3898.712 us; speedup vs baseline: 1.3707x; 1.0084x over previous
//
#include <hip/hip_runtime.h>
#include <cstdio>
#include <cmath>

#define HIDDEN 768
#define HEADS 8
#define DHEAD 96
#define NLAYERS 2
#define HH (HIDDEN * HIDDEN)

typedef unsigned short u16;
typedef unsigned int u32;
typedef __attribute__((ext_vector_type(8))) short bf16x8;
typedef __attribute__((ext_vector_type(4))) float f32x4;

__device__ __forceinline__ u16 f2b(float f) {
    u32 u = __float_as_uint(f);
    u32 r = (u + 0x7FFFu + ((u >> 16) & 1u)) >> 16;
    return (u16)r;
}
__device__ __forceinline__ float b2f(u16 v) { return __uint_as_float(((u32)v) << 16); }

// ================================================================== MFMA GEMM
// C[M,N] = act(A[M,K] @ Wt[N,K]^T + bias). A, Wt bf16 (u16) row-major,
// K contiguous for both. M multiple of 128, N multiple of 128, K multiple of 32.
// 128x128 tile, BK=32, 256 threads (4 waves, 2x2 of 64x64), 16x16x32 MFMA.
// LDS chunk swizzle s(r)=(r>>1)&3 keeps frag reads at 2-way (free).
template<int OUTF, int OUTB, int ACT>
__global__ __launch_bounds__(256, 3)
void gemm_mfma(const u16* __restrict__ A, const u16* __restrict__ Wt,
               const float* __restrict__ bias,
               float* __restrict__ Cf, u16* __restrict__ Cb,
               int M, int N, int K)
{
    __shared__ u16 As[128 * 32];
    __shared__ u16 Bs[128 * 32];
    const int tid = threadIdx.x;
    const int lane = tid & 63;
    const int wave = tid >> 6;
    const long m0 = (long)blockIdx.x * 128;
    const long n0 = (long)blockIdx.y * 128;
    const int wm = (wave & 1) * 64;
    const int wn = (wave >> 1) * 64;

    f32x4 acc[4][4];
#pragma unroll
    for (int i = 0; i < 4; i++)
#pragma unroll
        for (int j = 0; j < 4; j++) acc[i][j] = (f32x4){0.f, 0.f, 0.f, 0.f};

    const int r0 = tid >> 2, p0 = tid & 3;
    const int g0 = p0 ^ ((r0 >> 1) & 3);
    const int r1 = r0 + 64;
    const int g1 = p0 ^ ((r1 >> 1) & 3);
    const u16* ga0 = A + (m0 + r0) * (long)K + g0 * 8;
    const u16* ga1 = A + (m0 + r1) * (long)K + g1 * 8;
    const u16* gb0 = Wt + (n0 + r0) * (long)K + g0 * 8;
    const u16* gb1 = Wt + (n0 + r1) * (long)K + g1 * 8;
    u16* la0 = As + tid * 8;
    u16* la1 = As + (tid + 256) * 8;
    u16* lb0 = Bs + tid * 8;
    u16* lb1 = Bs + (tid + 256) * 8;

    for (int k0 = 0; k0 < K; k0 += 32) {
        __builtin_amdgcn_global_load_lds((const __attribute__((address_space(1))) void*)(ga0 + k0),
                                         (__attribute__((address_space(3))) void*)la0, 16, 0, 0);
        __builtin_amdgcn_global_load_lds((const __attribute__((address_space(1))) void*)(ga1 + k0),
                                         (__attribute__((address_space(3))) void*)la1, 16, 0, 0);
        __builtin_amdgcn_global_load_lds((const __attribute__((address_space(1))) void*)(gb0 + k0),
                                         (__attribute__((address_space(3))) void*)lb0, 16, 0, 0);
        __builtin_amdgcn_global_load_lds((const __attribute__((address_space(1))) void*)(gb1 + k0),
                                         (__attribute__((address_space(3))) void*)lb1, 16, 0, 0);
        __syncthreads();

        bf16x8 af[4], bfr[4];
        const int q = lane >> 4;
        const int lr = lane & 15;
#pragma unroll
        for (int i = 0; i < 4; i++) {
            int rr = wm + i * 16 + lr;
            af[i] = *(const bf16x8*)(As + rr * 32 + ((q ^ ((rr >> 1) & 3)) * 8));
            int rn = wn + i * 16 + lr;
            bfr[i] = *(const bf16x8*)(Bs + rn * 32 + ((q ^ ((rn >> 1) & 3)) * 8));
        }
#pragma unroll
        for (int i = 0; i < 4; i++)
#pragma unroll
            for (int j = 0; j < 4; j++)
                acc[i][j] = __builtin_amdgcn_mfma_f32_16x16x32_bf16(af[i], bfr[j], acc[i][j], 0, 0, 0);
        __syncthreads();
    }

    const int lc = lane & 15, lq = lane >> 4;
#pragma unroll
    for (int j = 0; j < 4; j++) {
        long col = n0 + wn + j * 16 + lc;
        float bv = bias ? bias[col] : 0.f;
#pragma unroll
        for (int i = 0; i < 4; i++) {
#pragma unroll
            for (int rg = 0; rg < 4; rg++) {
                long row = m0 + wm + i * 16 + lq * 4 + rg;
                float v = acc[i][j][rg] + bv;
                if (ACT) v = fmaxf(v, 0.f);
                if (OUTF) Cf[row * N + col] = v;
                if (OUTB) Cb[row * N + col] = f2b(v);
            }
        }
    }
}

// ============================================================ MFMA GEMM + skip
// o = A@Wt^T + bias; v = relu(beta*o + (1-beta)*b2f(hprev)); hout bf16 (rows <
// nReal only); if OUTF also writes v as f32 to outf. hprev/hout may alias (each
// element read+written by its owning thread only).
template<int OUTF>
__global__ __launch_bounds__(256, 3)
void gemm_skip(const u16* __restrict__ A, const u16* __restrict__ Wt,
               const float* __restrict__ bias, const u16* __restrict__ hprev,
               const float* __restrict__ sp, u16* __restrict__ hout,
               float* __restrict__ outf, int M, int N, int K, int nReal)
{
    __shared__ u16 As[128 * 32];
    __shared__ u16 Bs[128 * 32];
    const int tid = threadIdx.x;
    const int lane = tid & 63;
    const int wave = tid >> 6;
    const long m0 = (long)blockIdx.x * 128;
    const long n0 = (long)blockIdx.y * 128;
    const int wm = (wave & 1) * 64;
    const int wn = (wave >> 1) * 64;

    f32x4 acc[4][4];
#pragma unroll
    for (int i = 0; i < 4; i++)
#pragma unroll
        for (int j = 0; j < 4; j++) acc[i][j] = (f32x4){0.f, 0.f, 0.f, 0.f};

    const int r0 = tid >> 2, p0 = tid & 3;
    const int g0 = p0 ^ ((r0 >> 1) & 3);
    const int r1 = r0 + 64;
    const int g1 = p0 ^ ((r1 >> 1) & 3);
    const u16* ga0 = A + (m0 + r0) * (long)K + g0 * 8;
    const u16* ga1 = A + (m0 + r1) * (long)K + g1 * 8;
    const u16* gb0 = Wt + (n0 + r0) * (long)K + g0 * 8;
    const u16* gb1 = Wt + (n0 + r1) * (long)K + g1 * 8;
    u16* la0 = As + tid * 8;
    u16* la1 = As + (tid + 256) * 8;
    u16* lb0 = Bs + tid * 8;
    u16* lb1 = Bs + (tid + 256) * 8;

    for (int k0 = 0; k0 < K; k0 += 32) {
        __builtin_amdgcn_global_load_lds((const __attribute__((address_space(1))) void*)(ga0 + k0),
                                         (__attribute__((address_space(3))) void*)la0, 16, 0, 0);
        __builtin_amdgcn_global_load_lds((const __attribute__((address_space(1))) void*)(ga1 + k0),
                                         (__attribute__((address_space(3))) void*)la1, 16, 0, 0);
        __builtin_amdgcn_global_load_lds((const __attribute__((address_space(1))) void*)(gb0 + k0),
                                         (__attribute__((address_space(3))) void*)lb0, 16, 0, 0);
        __builtin_amdgcn_global_load_lds((const __attribute__((address_space(1))) void*)(gb1 + k0),
                                         (__attribute__((address_space(3))) void*)lb1, 16, 0, 0);
        __syncthreads();

        bf16x8 af[4], bfr[4];
        const int q = lane >> 4;
        const int lr = lane & 15;
#pragma unroll
        for (int i = 0; i < 4; i++) {
            int rr = wm + i * 16 + lr;
            af[i] = *(const bf16x8*)(As + rr * 32 + ((q ^ ((rr >> 1) & 3)) * 8));
            int rn = wn + i * 16 + lr;
            bfr[i] = *(const bf16x8*)(Bs + rn * 32 + ((q ^ ((rn >> 1) & 3)) * 8));
        }
#pragma unroll
        for (int i = 0; i < 4; i++)
#pragma unroll
            for (int j = 0; j < 4; j++)
                acc[i][j] = __builtin_amdgcn_mfma_f32_16x16x32_bf16(af[i], bfr[j], acc[i][j], 0, 0, 0);
        __syncthreads();
    }

    const float beta = 1.f / (1.f + expf(-sp[0]));
    const int lc = lane & 15, lq = lane >> 4;
#pragma unroll
    for (int j = 0; j < 4; j++) {
        long col = n0 + wn + j * 16 + lc;
        float bv = bias[col];
#pragma unroll
        for (int i = 0; i < 4; i++) {
#pragma unroll
            for (int rg = 0; rg < 4; rg++) {
                long row = m0 + wm + i * 16 + lq * 4 + rg;
                if (row < nReal) {
                    float o = acc[i][j][rg] + bv;
                    float v = beta * o + (1.f - beta) * b2f(hprev[row * N + col]);
                    v = fmaxf(v, 0.f);
                    hout[row * N + col] = f2b(v);
                    if (OUTF) outf[row * N + col] = v;
                }
            }
        }
    }
}

// ================================================================== f32 GEMM
// small combined-weight GEMMs: M=768, N=96, K=96, batch=heads.
// OUTT=1: write transposed bf16 directly into weight slot:
//   Ct[(bz*N + gn)*M + gm] = f2b(v)   (slot layout [out][in], in contiguous)
template<int ACT, int OUTT>
__global__ void gemm_f32(const float* __restrict__ A, int lda, long sA,
                         const float* __restrict__ W, int ldw, long sW,
                         const float* __restrict__ bias, long sB,
                         float* __restrict__ C, int ldc, long sC,
                         u16* __restrict__ Ct,
                         int M, int N, int K)
{
    int bz = blockIdx.z;
    A += (long)bz * sA;
    W += (long)bz * sW;
    if (!OUTT) C += (long)bz * sC;
    if (bias) bias += (long)bz * sB;

    __shared__ float Ash[16][65];
    __shared__ float Wsh[16][65];

    int tid = threadIdx.x;
    int tx = tid & 15, ty = tid >> 4;
    int m0 = blockIdx.x * 64, n0 = blockIdx.y * 64;
    float acc[4][4] = {};

    for (int k0 = 0; k0 < K; k0 += 16) {
#pragma unroll
        for (int i = 0; i < 4; i++) {
            int t = tid + i * 256;
            int mm = t >> 4, kk = t & 15;
            int gm = m0 + mm;
            Ash[kk][mm] = (gm < M) ? A[(long)gm * lda + (k0 + kk)] : 0.f;
        }
#pragma unroll
        for (int i = 0; i < 4; i++) {
            int t = tid + i * 256;
            int kk = t >> 6, nn = t & 63;
            int gn = n0 + nn;
            Wsh[kk][nn] = (gn < N) ? W[(long)(k0 + kk) * ldw + gn] : 0.f;
        }
        __syncthreads();
#pragma unroll
        for (int kk = 0; kk < 16; kk++) {
            float a[4], w[4];
#pragma unroll
            for (int i = 0; i < 4; i++) a[i] = Ash[kk][ty * 4 + i];
#pragma unroll
            for (int j = 0; j < 4; j++) w[j] = Wsh[kk][tx * 4 + j];
#pragma unroll
            for (int i = 0; i < 4; i++)
#pragma unroll
                for (int j = 0; j < 4; j++) acc[i][j] = fmaf(a[i], w[j], acc[i][j]);
        }
        __syncthreads();
    }
#pragma unroll
    for (int i = 0; i < 4; i++) {
        int gm = m0 + ty * 4 + i;
        if (gm >= M) continue;
#pragma unroll
        for (int j = 0; j < 4; j++) {
            int gn = n0 + tx * 4 + j;
            if (gn >= N) continue;
            float v = acc[i][j];
            if (bias) v += bias[gn];
            if (ACT == 1) v = fmaxf(v, 0.f);
            if (OUTT)
                Ct[(long)(bz * N + gn) * M + gm] = f2b(v);
            else
                C[(long)gm * ldc + gn] = v;
        }
    }
}

// ================================================================== prep
// f32 [768][768] -> bf16 [768][768] transposed, batched
__global__ void transpose_f2b(const float* __restrict__ src, long sStride,
                              u16* __restrict__ dst, long dStride)
{
    __shared__ float t[32][33];
    int z = blockIdx.z;
    src += (long)z * sStride;
    dst += (long)z * dStride;
    int bx = blockIdx.x * 32, by = blockIdx.y * 32;
    int x = threadIdx.x, y = threadIdx.y;  // 32 x 8
#pragma unroll
    for (int i = 0; i < 32; i += 8)
        t[y + i][x] = src[(long)(by + y + i) * 768 + bx + x];
    __syncthreads();
#pragma unroll
    for (int i = 0; i < 32; i += 8)
        dst[(long)(bx + y + i) * 768 + by + x] = f2b(t[x][y + i]);
}

// combined bias: bc[combo][h*96+j] = sum_d kb_slice[h*96+d] * R[l,e,h,d,j]
__global__ void bias_comb_k(const float* __restrict__ kb, const float* __restrict__ aR,
                            const float* __restrict__ mR, float* __restrict__ bc)
{
    int idx = blockIdx.x * blockDim.x + threadIdx.x;
    if (idx >= 12 * 768) return;
    int combo = idx / 768;
    int x = idx % 768;
    int h = x / 96, j = x % 96;
    int c6 = combo % 6;
    int l = c6 / 3, e = c6 % 3;
    int kind = (combo < 6) ? 0 : 2;
    int st = (e == 1) ? 1 : 0;
    const float* R = ((combo < 6) ? aR : mR) + ((long)(l * 3 + e) * 8 + h) * 9216;
    const float* kbp = kb + ((long)(l * 2 + st) * 4 + kind) * 768 + h * 96;
    float s = 0.f;
#pragma unroll 8
    for (int d = 0; d < 96; d++) s = fmaf(kbp[d], R[d * 96 + j], s);
    bc[idx] = s;
}

// x f32 -> bf16, zero-fill pad rows
__global__ void conv_pad(const float* __restrict__ src, u16* __restrict__ dst,
                         long nReal, long nPad)
{
    long i = blockIdx.x * (long)blockDim.x + threadIdx.x;
    if (i >= nPad) return;
    dst[i] = (i < nReal) ? f2b(src[i]) : (u16)0;
}

// ================================================================== edge ops
__device__ __forceinline__ float bdot(u32 a, u32 b, float s) {
    float al = __uint_as_float(a << 16);
    float ah = __uint_as_float(a & 0xffff0000u);
    float bl = __uint_as_float(b << 16);
    float bh = __uint_as_float(b & 0xffff0000u);
    return fmaf(ah, bh, fmaf(al, bl, s));
}

__global__ void edge_logits(const u16* __restrict__ q, const u16* __restrict__ kt,
                            const int* __restrict__ src, const int* __restrict__ dst,
                            const float* __restrict__ prel, float* __restrict__ out,
                            int ne)
{
    int idx = blockIdx.x * blockDim.x + threadIdx.x;
    if (idx >= ne * HEADS) return;
    int e = idx >> 3, h = idx & 7;
    const u16* qr = q + (long)dst[e] * HIDDEN + h * DHEAD;
    const u16* kr = kt + (long)src[e] * HIDDEN + h * DHEAD;
    float s = 0.f;
#pragma unroll
    for (int c = 0; c < 12; c++) {
        uint4 qv = *(const uint4*)(qr + c * 8);
        uint4 kv = *(const uint4*)(kr + c * 8);
        s = bdot(qv.x, kv.x, s);
        s = bdot(qv.y, kv.y, s);
        s = bdot(qv.z, kv.z, s);
        s = bdot(qv.w, kv.w, s);
    }
    out[idx] = s * prel[h] * 0.1020620726159658f;  // 1/sqrt(96)
}

// ============================================================== CSR softmax
// One wave per dst node: in-place normalize alpha over the node's CSR row,
// per head. Lanes: h = lane>>3 (8 heads), slot = lane&7 (edge-parallel).
// No atomics; exact two-pass max/sum like the reference.
__global__ void csr_softmax_k(const int* __restrict__ rs, const int* __restrict__ ep,
                              float* __restrict__ alpha, int nnodes)
{
    int wid = (blockIdx.x * blockDim.x + threadIdx.x) >> 6;
    if (wid >= nnodes) return;
    const int lane = threadIdx.x & 63;
    const int h = lane >> 3, slot = lane & 7;
    const int b = rs[wid], en = rs[wid + 1];

    float m = -INFINITY;
    for (int i = b + slot; i < en; i += 8)
        m = fmaxf(m, alpha[(long)ep[i] * HEADS + h]);
    m = fmaxf(m, __shfl_xor(m, 1));
    m = fmaxf(m, __shfl_xor(m, 2));
    m = fmaxf(m, __shfl_xor(m, 4));

    float s = 0.f;
    for (int i = b + slot; i < en; i += 8)
        s += expf(alpha[(long)ep[i] * HEADS + h] - m);
    s += __shfl_xor(s, 1);
    s += __shfl_xor(s, 2);
    s += __shfl_xor(s, 4);
    const float inv = 1.f / (s + 1e-16f);

    for (int i = b + slot; i < en; i += 8) {
        long idx = (long)ep[i] * HEADS + h;
        alpha[idx] = expf(alpha[idx] - m) * inv;
    }
}

// ================================================================== CSR build
__global__ void hist_k(const int* __restrict__ dst, int* __restrict__ cnt, int ne) {
    int i = blockIdx.x * blockDim.x + threadIdx.x;
    if (i < ne) atomicAdd(&cnt[dst[i]], 1);
}

// single-block exclusive scan, 1024 thr x 8 elems/chunk; out has n+1 entries
__global__ void excl_scan_k(const int* __restrict__ in, int* __restrict__ out, int n)
{
    __shared__ int lds[1024];
    __shared__ int carry_s;
    const int tid = threadIdx.x;
    if (tid == 0) carry_s = 0;
    __syncthreads();
    for (int base = 0; base < n; base += 8192) {
        int v[8];
        int s = 0;
        const int i0 = base + tid * 8;
#pragma unroll
        for (int j = 0; j < 8; j++) {
            v[j] = s;
            int idx = i0 + j;
            s += (idx < n) ? in[idx] : 0;
        }
        lds[tid] = s;
        __syncthreads();
        int cb = carry_s;
        for (int ofs = 1; ofs < 1024; ofs <<= 1) {
            int t = (tid >= ofs) ? lds[tid - ofs] : 0;
            __syncthreads();
            if (tid >= ofs) lds[tid] += t;
            __syncthreads();
        }
        int excl = cb + (tid ? lds[tid - 1] : 0);
#pragma unroll
        for (int j = 0; j < 8; j++) {
            int idx = i0 + j;
            if (idx < n) out[idx] = excl + v[j];
        }
        __syncthreads();
        if (tid == 0) carry_s = cb + lds[1023];
        __syncthreads();
    }
    if (tid == 0) out[n] = carry_s;
}

__global__ void scatter_perm_k(const int* __restrict__ dst, const int* __restrict__ rs,
                               int* __restrict__ cur, int* __restrict__ ep, int ne) {
    int i = blockIdx.x * blockDim.x + threadIdx.x;
    if (i < ne) {
        int d = dst[i];
        int p = rs[d] + atomicAdd(&cur[d], 1);
        ep[p] = i;
    }
}

// ================================================================== gather
// One block per dst node; 192 threads x 4 channels. Accumulates
// sum_e alpha_e * vt[src_e] (alpha already normalized) over up to two CSR edge
// sets, applies GELU, writes bf16 row (pad rows -> 0).
__device__ __forceinline__ void fma4bf(uint2 pv, float a, float acc[4]) {
    acc[0] = fmaf(a, __uint_as_float(pv.x << 16), acc[0]);
    acc[1] = fmaf(a, __uint_as_float(pv.x & 0xffff0000u), acc[1]);
    acc[2] = fmaf(a, __uint_as_float(pv.y << 16), acc[2]);
    acc[3] = fmaf(a, __uint_as_float(pv.y & 0xffff0000u), acc[3]);
}

template<int NSET>
__global__ void gather_gelu_k(
    const int* __restrict__ rs0, const int* __restrict__ ep0, const int* __restrict__ src0,
    const float* __restrict__ al0, const u16* __restrict__ vt0,
    const int* __restrict__ rs1, const int* __restrict__ ep1, const int* __restrict__ src1,
    const float* __restrict__ al1, const u16* __restrict__ vt1,
    u16* __restrict__ out, int nsReal)
{
    const int node = blockIdx.x;
    const int tid = threadIdx.x;           // 192
    const int h = tid / 24;                // 24 threads per head (96 ch / 4)
    float acc[4] = {0.f, 0.f, 0.f, 0.f};
    if (node < nsReal) {
        {
            const int b = rs0[node], en = rs0[node + 1];
            for (int i = b; i < en; i++) {
                const int eid = ep0[i];
                const float a = al0[(long)eid * HEADS + h];
                const uint2 pv = *(const uint2*)(vt0 + (long)src0[eid] * HIDDEN + tid * 4);
                fma4bf(pv, a, acc);
            }
        }
        if (NSET == 2) {
            const int b = rs1[node], en = rs1[node + 1];
            for (int i = b; i < en; i++) {
                const int eid = ep1[i];
                const float a = al1[(long)eid * HEADS + h];
                const uint2 pv = *(const uint2*)(vt1 + (long)src1[eid] * HIDDEN + tid * 4);
                fma4bf(pv, a, acc);
            }
        }
    }
    // exact GELU, pack to bf16, single 8B store
    float g[4];
#pragma unroll
    for (int j = 0; j < 4; j++)
        g[j] = 0.5f * acc[j] * (1.f + erff(acc[j] * 0.70710678118654752f));
    u32 w0 = (u32)f2b(g[0]) | ((u32)f2b(g[1]) << 16);
    u32 w1 = (u32)f2b(g[2]) | ((u32)f2b(g[3]) << 16);
    *(uint2*)(out + (long)node * HIDDEN + tid * 4) = make_uint2(w0, w1);
}

// ================================================================== host
static inline void mfma_bf16out(hipStream_t s, const u16* A, const u16* Wt,
                                const float* bias, u16* Cb, int M, int act) {
    dim3 grid(M / 128, HIDDEN / 128);
    if (act)
        gemm_mfma<0, 1, 1><<<grid, 256, 0, s>>>(A, Wt, bias, nullptr, Cb, M, HIDDEN, HIDDEN);
    else
        gemm_mfma<0, 1, 0><<<grid, 256, 0, s>>>(A, Wt, bias, nullptr, Cb, M, HIDDEN, HIDDEN);
}

extern "C" void kernel_launch(void* const* d_in, const int* in_sizes, int n_in,
                              void* d_out, int out_size, void* d_ws, size_t ws_size,
                              hipStream_t stream)
{
    const float* x0  = (const float*)d_in[0];
    const float* x1  = (const float*)d_in[1];
    const float* nlW = (const float*)d_in[2];
    const float* nlb = (const float*)d_in[3];
    const float* kW  = (const float*)d_in[4];   // [L,2,4,768,768]
    const float* kb  = (const float*)d_in[5];   // [L,2,4,768]
    const float* skp = (const float*)d_in[6];   // [L,2]
    const float* aR  = (const float*)d_in[7];   // [L,3,8,96,96]
    const float* mR  = (const float*)d_in[8];   // [L,3,8,96,96]
    const float* pR  = (const float*)d_in[9];   // [L,3,8]
    const int* esrc[3] = {(const int*)d_in[10], (const int*)d_in[12], (const int*)d_in[14]};
    const int* edst[3] = {(const int*)d_in[11], (const int*)d_in[13], (const int*)d_in[15]};
    const int EST[3] = {0, 1, 0};
    const int EDT[3] = {0, 0, 1};
    const int EN[3]  = {in_sizes[10], in_sizes[12], in_sizes[14]};

    const int NP = in_sizes[0] / HIDDEN;
    const int NA = in_sizes[1] / HIDDEN;
    const int ns[2]    = {NP, NA};
    const int nspad[2] = {(NP + 127) & ~127, (NA + 127) & ~127};

    // ---------------- workspace (bytes, 256-aligned) ----------------
    char* base = (char*)d_ws;
    size_t off = 0;
    auto alloc = [&](size_t bytes) -> void* {
        void* p = base + off;
        off += (bytes + 255) & ~(size_t)255;
        return p;
    };
    u16* hbf[2] = {(u16*)alloc((size_t)nspad[0] * HIDDEN * 2),
                   (u16*)alloc((size_t)nspad[1] * HIDDEN * 2)};
    u16* qbf[2] = {(u16*)alloc((size_t)nspad[0] * HIDDEN * 2),   // also x-bf16, gelu-bf16
                   (u16*)alloc((size_t)nspad[1] * HIDDEN * 2)};
    u16* ktvbase = (u16*)alloc((size_t)(2 * nspad[0] + nspad[1]) * HIDDEN * 2);
    u16* ktv[3] = {ktvbase, ktvbase + (size_t)nspad[0] * HIDDEN,
                   ktvbase + (size_t)(nspad[0] + nspad[1]) * HIDDEN};
    float* alphab[3];
    for (int e = 0; e < 3; e++) alphab[e] = (float*)alloc((size_t)EN[e] * HEADS * 4);
    int* csr_rs[3];
    int* csr_ep[3];
    for (int e = 0; e < 3; e++) {
        csr_rs[e] = (int*)alloc((size_t)(ns[EDT[e]] + 1) * 4);
        csr_ep[e] = (int*)alloc((size_t)EN[e] * 4);
    }
    int nsMax = ns[0] > ns[1] ? ns[0] : ns[1];
    int* cursor = (int*)alloc((size_t)nsMax * 4);
    u16* Wbf     = (u16*)alloc((size_t)22 * HH * 2);   // transposed bf16 weights
    float* bcomb = (float*)alloc((size_t)12 * 768 * 4);
    if (off > ws_size)
        fprintf(stderr, "kernel_launch: ws too small: need %zu have %zu\n", off, ws_size);

    auto wslot = [&](int s) { return Wbf + (size_t)s * HH; };

    // ---------------- CSR build (edges static across layers) ----------------
    for (int e = 0; e < 3; e++) {
        int dt = EDT[e], Ne = EN[e], nd = ns[dt];
        hipMemsetAsync(cursor, 0, (size_t)nd * 4, stream);
        hist_k<<<(Ne + 255) / 256, 256, 0, stream>>>(edst[e], cursor, Ne);
        excl_scan_k<<<1, 1024, 0, stream>>>(cursor, csr_rs[e], nd);
        hipMemsetAsync(cursor, 0, (size_t)nd * 4, stream);
        scatter_perm_k<<<(Ne + 255) / 256, 256, 0, stream>>>(edst[e], csr_rs[e], cursor,
                                                             csr_ep[e], Ne);
    }

    // ---------------- weight prep ----------------
    // combined kt/vt weights: Wc = Wk_slice[768x96] @ R[h][96x96], head-batched,
    // written transposed+bf16 directly into slots 10..15 (kt) / 16..21 (vt)
    for (int l = 0; l < NLAYERS; l++)
        for (int e = 0; e < 3; e++) {
            int st = EST[e];
            {   // kt (kind 0, aR)
                const float* Ap = kW + ((size_t)(l * 2 + st) * 4 + 0) * HH;
                const float* Wp = aR + ((size_t)(l * 3 + e)) * 8 * 9216;
                dim3 g(12, 2, 8);
                gemm_f32<0, 1><<<g, 256, 0, stream>>>(Ap, 768, 96, Wp, 96, 9216,
                                                      nullptr, 0, nullptr, 0, 0,
                                                      wslot(10 + l * 3 + e), 768, 96, 96);
            }
            {   // vt (kind 2, mR)
                const float* Ap = kW + ((size_t)(l * 2 + st) * 4 + 2) * HH;
                const float* Wp = mR + ((size_t)(l * 3 + e)) * 8 * 9216;
                dim3 g(12, 2, 8);
                gemm_f32<0, 1><<<g, 256, 0, stream>>>(Ap, 768, 96, Wp, 96, 9216,
                                                      nullptr, 0, nullptr, 0, 0,
                                                      wslot(16 + l * 3 + e), 768, 96, 96);
            }
        }
    bias_comb_k<<<(12 * 768 + 255) / 256, 256, 0, stream>>>(kb, aR, mR, bcomb);

    // transpose-convert plain weights to bf16 [N][K]
    {
        dim3 b(32, 8);
        dim3 g(24, 24, 2);
        transpose_f2b<<<g, b, 0, stream>>>(nlW, HH, wslot(0), HH);          // node: slots 0,1
        g.z = 4;
        transpose_f2b<<<g, b, 0, stream>>>(kW + (size_t)1 * HH, 4 * (long)HH, wslot(2), HH); // Q: 2..5
        transpose_f2b<<<g, b, 0, stream>>>(kW + (size_t)3 * HH, 4 * (long)HH, wslot(6), HH); // A: 6..9
    }

    // ---------------- input projection ----------------
    for (int t = 0; t < 2; t++) {
        long nPad = (long)nspad[t] * HIDDEN, nReal = (long)ns[t] * HIDDEN;
        conv_pad<<<(int)((nPad + 255) / 256), 256, 0, stream>>>(t ? x1 : x0, qbf[t], nReal, nPad);
        mfma_bf16out(stream, qbf[t], wslot(t), nlb + (size_t)t * 768, hbf[t], nspad[t], 1);
    }

    // ---------------- layers ----------------
    for (int l = 0; l < NLAYERS; l++) {
        // phase A: Q + kt projections, logits, CSR segment softmax
        for (int t = 0; t < 2; t++)
            mfma_bf16out(stream, hbf[t], wslot(2 + l * 2 + t),
                         kb + ((size_t)(l * 2 + t) * 4 + 1) * 768, qbf[t], nspad[t], 0);
        for (int e = 0; e < 3; e++) {
            int st = EST[e], dt = EDT[e], Ne = EN[e];
            mfma_bf16out(stream, hbf[st], wslot(10 + l * 3 + e),
                         bcomb + (size_t)(l * 3 + e) * 768, ktv[e], nspad[st], 0);
            int nthr = Ne * HEADS;
            edge_logits<<<(nthr + 255) / 256, 256, 0, stream>>>(
                qbf[dt], ktv[e], esrc[e], edst[e],
                pR + ((size_t)l * 3 + e) * HEADS, alphab[e], Ne);
            // one wave per node (4 waves / 256-thread block)
            csr_softmax_k<<<(ns[dt] + 3) / 4, 256, 0, stream>>>(
                csr_rs[e], csr_ep[e], alphab[e], ns[dt]);
        }
        // phase B: vt projections, then CSR gather (fused GELU -> bf16)
        for (int e = 0; e < 3; e++) {
            int st = EST[e];
            mfma_bf16out(stream, hbf[st], wslot(16 + l * 3 + e),
                         bcomb + (size_t)(6 + l * 3 + e) * 768, ktv[e], nspad[st], 0);
        }
        // paper aggr: edge sets 0 (pp) and 1 (ap)
        gather_gelu_k<2><<<nspad[0], 192, 0, stream>>>(
            csr_rs[0], csr_ep[0], esrc[0], alphab[0], ktv[0],
            csr_rs[1], csr_ep[1], esrc[1], alphab[1], ktv[1],
            qbf[0], ns[0]);
        // author aggr: edge set 2 (pa)
        gather_gelu_k<1><<<nspad[1], 192, 0, stream>>>(
            csr_rs[2], csr_ep[2], esrc[2], alphab[2], ktv[2],
            nullptr, nullptr, nullptr, nullptr, nullptr,
            qbf[1], ns[1]);
        // phase C: A-projection with fused skip/relu epilogue
        for (int t = 0; t < 2; t++) {
            dim3 grid(nspad[t] / 128, HIDDEN / 128);
            const float* bias = kb + ((size_t)(l * 2 + t) * 4 + 3) * 768;
            const float* sp = skp + (size_t)l * 2 + t;
            if (l == NLAYERS - 1) {
                float* outf = (float*)d_out + (t == 0 ? 0 : (size_t)NP * HIDDEN);
                gemm_skip<1><<<grid, 256, 0, stream>>>(qbf[t], wslot(6 + l * 2 + t), bias,
                                                       hbf[t], sp, hbf[t], outf,
                                                       nspad[t], HIDDEN, HIDDEN, ns[t]);
            } else {
                gemm_skip<0><<<grid, 256, 0, stream>>>(qbf[t], wslot(6 + l * 2 + t), bias,
                                                       hbf[t], sp, hbf[t], nullptr,
                                                       nspad[t], HIDDEN, HIDDEN, ns[t]);
            }
        }
    }
}